// Round 11
// baseline (79.204 us; speedup 1.0000x reference)
//
#include <hip/hip_runtime.h>
#include <hip/hip_bf16.h>

#define A_N 8
#define C_N 256
#define H_N 80
#define W_N 108
#define P_N (H_N * W_N)      // 8640
#define P4_N (P_N / 4)       // 2160 float4 columns per plane
#define O_N 7
#define MH 256
#define MW 256
#define OUT_HW 256
#define TPA 34               // 64-px4 tiles per agent (34*64 = 2176 >= 2160)

__device__ __forceinline__ float sigmoidf_(float zv) {
    return 1.0f / (1.0f + __expf(-zv));
}

// ---------------------------------------------------------------------------
// Fused resize + conv, global_load_lds pipelined (T3 2-phase, counted vmcnt).
// Grid 8*34 = 272 blocks x 256 thr (4 waves). Block = one 64-px4 tile.
// 16 steps x 16 channels staged to LDS (double-buffered 2x16KB); per step
// each wave issues 4 global_load_lds (1KB each: one channel row).
// vmcnt(4) keeps the next step's 4 loads in flight across the barrier.
// Each wave stages AND computes only its own 4 channel slots -> no cross-wave
// data sharing until the epilogue (which is __syncthreads()-protected).
// ---------------------------------------------------------------------------
__global__ void k_conv(const float* __restrict__ x, const float* __restrict__ masks,
                       const float* __restrict__ w, const float* __restrict__ b,
                       float* __restrict__ z, float* __restrict__ ssolo)
{
    __shared__ float s_x[8192];    // 2 x 16KB staging buffers
    __shared__ float s_w[2048];    // w transposed [c][8]: 256 ch x 8
    __shared__ float s_cm[256];    // resized mask for this tile's 256 px

    const int tid  = threadIdx.x;
    const int lane = tid & 63;
    const int wid  = tid >> 6;
    const int a    = blockIdx.x / TPA;
    const int t    = blockIdx.x - a * TPA;

    // ---- prologue A: stage w -> LDS as [c][8] (all 2048 entries) ----
    #pragma unroll
    for (int k = 0; k < 8; ++k) {
        const int idx = k * 256 + tid;
        const int c = idx >> 3, o = idx & 7;
        s_w[idx] = (o < O_N) ? w[o * C_N + c] : 0.0f;
    }

    // ---- prologue B: antialias triangle resize (jax.image.resize), fixed
    //      7x5 window, 35 independent L2 loads per thread ----
    {
        const int ppx = t * 256 + tid;
        const int pc  = min(ppx, P_N - 1);
        const int oy = pc / W_N, ox = pc - oy * W_N;
        const float ksy = 256.0f / 80.0f;
        const float ksx = 256.0f / 108.0f;
        const float rky = 0.3125f;          // 80/256 exact
        const float rkx = 0.421875f;        // 108/256 exact
        const float sfy = ((float)oy + 0.5f) * ksy - 0.5f;
        const float sfx = ((float)ox + 0.5f) * ksx - 0.5f;
        const int iyS = (int)ceilf(sfy - ksy);
        const int ixS = (int)ceilf(sfx - ksx);

        float wxv[5];
        float wxs = 0.0f;
        #pragma unroll
        for (int q = 0; q < 5; ++q) {
            const int ix = ixS + q;
            float wv = fmaxf(0.0f, 1.0f - fabsf(sfx - (float)ix) * rkx);
            wv = (ix >= 0 && ix < MW) ? wv : 0.0f;
            wxv[q] = wv;
            wxs += wv;
        }
        const float* mp = masks + (size_t)a * (MH * MW);
        float acm = 0.0f, wys = 0.0f;
        #pragma unroll
        for (int r = 0; r < 7; ++r) {
            const int iy = iyS + r;
            float wy = fmaxf(0.0f, 1.0f - fabsf(sfy - (float)iy) * rky);
            wy = (iy >= 0 && iy < MH) ? wy : 0.0f;
            wys += wy;
            const float* row = mp + min(max(iy, 0), MH - 1) * MW;
            float rs = 0.0f;
            #pragma unroll
            for (int q = 0; q < 5; ++q)
                rs = fmaf(wxv[q], row[min(max(ixS + q, 0), MW - 1)], rs);
            acm = fmaf(wy, rs, acm);
        }
        s_cm[tid] = acm / (wys * wxs);
    }
    __syncthreads();   // w + cm visible; prologue vmem drained

    const int px4  = t * 64 + lane;
    const int px4c = min(px4, P4_N - 1);           // per-lane clamp (gl_lds src is per-lane)
    const float* xa = x + (size_t)a * C_N * P_N;

    const float4 cm4 = make_float4(s_cm[lane * 4], s_cm[lane * 4 + 1],
                                   s_cm[lane * 4 + 2], s_cm[lane * 4 + 3]);

    float4 acc[O_N];
    #pragma unroll
    for (int o = 0; o < O_N; ++o) acc[o] = make_float4(0.f, 0.f, 0.f, 0.f);

    // wave wid stages/computes channels step*16 + r*4 + wid, r = 0..3
#define STAGE(dstofs, step)                                                    \
    { _Pragma("unroll")                                                        \
      for (int r = 0; r < 4; ++r) {                                            \
          const int c = (step) * 16 + r * 4 + wid;                             \
          const float* gs = xa + (size_t)c * P4_N * 4 + (size_t)px4c * 4;      \
          __builtin_amdgcn_global_load_lds(                                    \
              (const __attribute__((address_space(1))) void*)gs,               \
              (__attribute__((address_space(3))) void*)(s_x + (dstofs) + (r * 4 + wid) * 256), \
              16, 0, 0);                                                       \
      } }

#define COMPS(srcofs, step)                                                    \
    { _Pragma("unroll")                                                        \
      for (int r = 0; r < 4; ++r) {                                            \
          const int c = (step) * 16 + r * 4 + wid;                             \
          float4 v = *reinterpret_cast<const float4*>(                         \
                         s_x + (srcofs) + (r * 4 + wid) * 256 + lane * 4);     \
          v.x += cm4.x; v.y += cm4.y; v.z += cm4.z; v.w += cm4.w;              \
          const float* wc = s_w + c * 8;                                       \
          _Pragma("unroll")                                                    \
          for (int o = 0; o < O_N; ++o) {                                      \
              const float wv = wc[o];                                          \
              acc[o].x = fmaf(wv, v.x, acc[o].x);                              \
              acc[o].y = fmaf(wv, v.y, acc[o].y);                              \
              acc[o].z = fmaf(wv, v.z, acc[o].z);                              \
              acc[o].w = fmaf(wv, v.w, acc[o].w);                              \
          }                                                                    \
      } }

    STAGE(0, 0)
    #pragma unroll
    for (int s = 0; s < 16; ++s) {
        const int bo = (s & 1) * 4096;
        const int bn = ((s + 1) & 1) * 4096;
        if (s < 15) {
            STAGE(bn, s + 1)
            asm volatile("s_waitcnt vmcnt(4)" ::: "memory");
        } else {
            asm volatile("s_waitcnt vmcnt(0)" ::: "memory");
        }
        __builtin_amdgcn_s_barrier();
        __builtin_amdgcn_sched_barrier(0);
        COMPS(bo, s)
        asm volatile("" ::: "memory");
        __builtin_amdgcn_s_barrier();
    }
#undef STAGE
#undef COMPS

    // ---- cross-wave reduce: reuse staging LDS (28KB <= 32KB).
    //      __syncthreads() drains each wave's lgkm before any overwrite. ----
    __syncthreads();
    float4* sred = reinterpret_cast<float4*>(s_x);
    #pragma unroll
    for (int o = 0; o < O_N; ++o)
        sred[(wid * 64 + lane) * O_N + o] = acc[o];
    __syncthreads();

    // 448 (px,o) pairs over 256 threads: STRIDED loop (r9 bug: `if (tid<448)`
    // covered only 256 pairs -> planes o=4..6 never stored).
    for (int pair = tid; pair < 64 * O_N; pair += 256) {
        const int px = pair & 63;
        const int o  = pair >> 6;
        const int pg = t * 64 + px;
        if (pg >= P4_N) continue;
        const float4 s0 = sred[(0 * 64 + px) * O_N + o];
        const float4 s1 = sred[(1 * 64 + px) * O_N + o];
        const float4 s2 = sred[(2 * 64 + px) * O_N + o];
        const float4 s3 = sred[(3 * 64 + px) * O_N + o];
        float4 zv;
        zv.x = s0.x + s1.x + s2.x + s3.x;
        zv.y = s0.y + s1.y + s2.y + s3.y;
        zv.z = s0.z + s1.z + s2.z + s3.z;
        zv.w = s0.w + s1.w + s2.w + s3.w;
        const float bo = b[o];
        const size_t ob = (size_t)(a * O_N + o) * P4_N + pg;
        reinterpret_cast<float4*>(z)[ob] = zv;
        float4 sv;
        sv.x = sigmoidf_(zv.x + bo);
        sv.y = sigmoidf_(zv.y + bo);
        sv.z = sigmoidf_(zv.z + bo);
        sv.w = sigmoidf_(zv.w + bo);
        reinterpret_cast<float4*>(ssolo)[ob] = sv;
    }
}

// ---------------------------------------------------------------------------
// Aggregation: per ego i, pixel p: saggr = sigmoid(b + sum_j adj[i,j]!=0 ?
//              zero-padded-bilinear(z[j], rel[i,j] @ [u,v,1]) : 0)
// z planes total 1.9 MB — L2-resident gathers. 1080 blocks x 64.
// ---------------------------------------------------------------------------
__launch_bounds__(64)
__global__ void k_aggr(const float* __restrict__ z, const float* __restrict__ rel,
                       const int* __restrict__ adj, const float* __restrict__ b,
                       float* __restrict__ saggr)
{
    const int i = blockIdx.x / 135;
    const int p = (blockIdx.x - i * 135) * 64 + threadIdx.x;
    const int vy = p / W_N, ux = p - vy * W_N;
    const float fu = (float)ux, fv = (float)vy;

    float acc[O_N];
    #pragma unroll
    for (int o = 0; o < O_N; ++o) acc[o] = b[o];

    for (int j = 0; j < A_N; ++j) {
        if (adj[i * A_N + j] == 0) continue;
        const float* M = rel + (i * A_N + j) * 6;
        float sx = M[0] * fu + M[1] * fv + M[2];
        float sy = M[3] * fu + M[4] * fv + M[5];
        if (!(sx > -1.0f && sx < (float)W_N && sy > -1.0f && sy < (float)H_N)) continue;
        float x0f = floorf(sx), y0f = floorf(sy);
        float wx = sx - x0f, wy = sy - y0f;
        int x0 = (int)x0f, y0 = (int)y0f;
        int x1 = x0 + 1,  y1 = y0 + 1;
        float w00 = (1.0f - wy) * (1.0f - wx), w01 = (1.0f - wy) * wx;
        float w10 = wy * (1.0f - wx),          w11 = wy * wx;
        if (x0 < 0)    { w00 = 0.0f; w10 = 0.0f; x0 = 0; }
        if (x1 >= W_N) { w01 = 0.0f; w11 = 0.0f; x1 = W_N - 1; }
        if (y0 < 0)    { w00 = 0.0f; w01 = 0.0f; y0 = 0; }
        if (y1 >= H_N) { w10 = 0.0f; w11 = 0.0f; y1 = H_N - 1; }
        const int i00 = y0 * W_N + x0, i01 = y0 * W_N + x1;
        const int i10 = y1 * W_N + x0, i11 = y1 * W_N + x1;
        const float* zj = z + j * O_N * P_N;
        #pragma unroll
        for (int o = 0; o < O_N; ++o) {
            const float* zp = zj + o * P_N;
            acc[o] += w00 * zp[i00] + w01 * zp[i01] + w10 * zp[i10] + w11 * zp[i11];
        }
    }
    const int ob = i * O_N * P_N + p;
    #pragma unroll
    for (int o = 0; o < O_N; ++o) saggr[ob + o * P_N] = sigmoidf_(acc[o]);
}

// ---------------------------------------------------------------------------
// Upsample: align_corners=True bilinear 80x108 -> 256x256, f32 out.
// 4 px/thread -> float4 stores; 7168 blocks x 256 exact.
// Output layout: [solo(8,7,256,256), aggr(8,7,256,256)] flat f32.
// ---------------------------------------------------------------------------
__launch_bounds__(256)
__global__ void k_upsample(const float* __restrict__ ssolo, const float* __restrict__ saggr,
                           float* __restrict__ out)
{
    const int idx = blockIdx.x * 256 + threadIdx.x;   // quad index
    int k = idx;
    const int oxq = k & 63;   k >>= 6;
    const int oy  = k & 255;  k >>= 8;
    const int o   = k % O_N;  k /= O_N;
    const int a   = k & 7;    k >>= 3;
    const int t   = k;        // 0 = solo, 1 = aggr

    const float* src = (t == 0 ? ssolo : saggr) + (a * O_N + o) * P_N;
    float syf = (float)oy * (79.0f / 255.0f);
    int y0 = (int)syf; y0 = min(y0, H_N - 2);
    float wy = syf - (float)y0;
    const float* r0 = src + y0 * W_N;
    const float* r1 = r0 + W_N;

    float res[4];
    #pragma unroll
    for (int q = 0; q < 4; ++q) {
        int ox = oxq * 4 + q;
        float sxf = (float)ox * (107.0f / 255.0f);
        int x0 = (int)sxf; x0 = min(x0, W_N - 2);
        float wx = sxf - (float)x0;
        float c0 = r0[x0]     * (1.0f - wy) + r1[x0]     * wy;
        float c1 = r0[x0 + 1] * (1.0f - wy) + r1[x0 + 1] * wy;
        res[q] = c0 * (1.0f - wx) + c1 * wx;
    }
    *reinterpret_cast<float4*>(out + (size_t)idx * 4) =
        make_float4(res[0], res[1], res[2], res[3]);
}

// ---------------------------------------------------------------------------
extern "C" void kernel_launch(void* const* d_in, const int* in_sizes, int n_in,
                              void* d_out, int out_size, void* d_ws, size_t ws_size,
                              hipStream_t stream)
{
    (void)in_sizes; (void)n_in; (void)out_size; (void)ws_size;
    const float* x    = (const float*)d_in[0];
    const float* rel  = (const float*)d_in[1];
    const int*   adj  = (const int*)d_in[2];
    const float* cmsk = (const float*)d_in[3];
    const float* wcls = (const float*)d_in[4];
    const float* bcls = (const float*)d_in[5];
    float* out = (float*)d_out;   // reference output dtype is float32

    float* ws    = (float*)d_ws;
    float* z     = ws;                          // 8*7*8640 = 483,840 f32
    float* ssolo = z     + A_N * O_N * P_N;
    float* saggr = ssolo + A_N * O_N * P_N;     // total ~5.8 MB

    k_conv    <<<A_N * TPA, 256, 0, stream>>>(x, cmsk, wcls, bcls, z, ssolo);
    k_aggr    <<<1080, 64, 0, stream>>>(z, rel, adj, bcls, saggr);
    k_upsample<<<7168, 256, 0, stream>>>(ssolo, saggr, out);
}